// Round 1
// baseline (71.356 us; speedup 1.0000x reference)
//
#include <hip/hip_runtime.h>

// One thread per 2x2 patch: simulate a 4-qubit circuit (16 complex amps,
// fully unrolled into registers), output <Z_q> for q=0..3.
//
// Index convention: amplitude m = i*8 + j*4 + k*2 + l where i..l are
// qubits 0..3 -> qubit q lives at bit (3-q), mask = 8 >> q.

__global__ __launch_bounds__(256) void qlayer_kernel(
    const float* __restrict__ x,     // (32, 256, 256, 1)
    const float* __restrict__ qw,    // (2, 4)
    float* __restrict__ out,         // (32, 128, 128, 4)
    int n_total)
{
    int n = blockIdx.x * blockDim.x + threadIdx.x;
    if (n >= n_total) return;

    int ow = n & 127;
    int oh = (n >> 7) & 127;
    int b  = n >> 14;

    // 2x2 stride-2 patch, row-major within patch
    const float* row0 = x + ((size_t)(b * 256 + 2 * oh) * 256 + 2 * ow);
    const float* row1 = row0 + 256;
    float2 p0 = *(const float2*)row0;   // angles 0, 1
    float2 p1 = *(const float2*)row1;   // angles 2, 3

    const float PI_4 = 0.78539816339744830962f;  // pi/4 = half-angle scale
    float ang[4] = { p0.x * PI_4, p0.y * PI_4, p1.x * PI_4, p1.y * PI_4 };

    // Per-qubit RY amplitudes on |0>: [cos, sin]
    float vc[4], vs[4];
#pragma unroll
    for (int q = 0; q < 4; ++q) {
        __sincosf(ang[q], &vs[q], &vc[q]);
    }

    // Product state (real), im = 0
    float re[16], im[16];
#pragma unroll
    for (int i = 0; i < 2; ++i) {
        float v0 = i ? vs[0] : vc[0];
#pragma unroll
        for (int j = 0; j < 2; ++j) {
            float v01 = v0 * (j ? vs[1] : vc[1]);
#pragma unroll
            for (int k = 0; k < 2; ++k) {
                float v012 = v01 * (k ? vs[2] : vc[2]);
#pragma unroll
                for (int l = 0; l < 2; ++l) {
                    int m = i * 8 + j * 4 + k * 2 + l;
                    re[m] = v012 * (l ? vs[3] : vc[3]);
                    im[m] = 0.0f;
                }
            }
        }
    }

    // Gate half-angle cos/sin for all (layer, qubit)
    float gc[8], gs[8];
#pragma unroll
    for (int i = 0; i < 8; ++i) {
        __sincosf(qw[i] * 0.5f, &gs[i], &gc[i]);
    }

#pragma unroll
    for (int l = 0; l < 2; ++l) {
        // RX(w) on each qubit: [[c, -is], [-is, c]]
#pragma unroll
        for (int q = 0; q < 4; ++q) {
            float c = gc[l * 4 + q];
            float s = gs[l * 4 + q];
            int mask = 8 >> q;
#pragma unroll
            for (int m = 0; m < 16; ++m) {
                if (m & mask) continue;
                int m1 = m | mask;
                float r0 = re[m],  i0 = im[m];
                float r1 = re[m1], i1 = im[m1];
                // new0 = c*a0 - i*s*a1 ; new1 = -i*s*a0 + c*a1
                re[m]  = c * r0 + s * i1;
                im[m]  = c * i0 - s * r1;
                re[m1] = c * r1 + s * i0;
                im[m1] = c * i1 - s * r0;
            }
        }
        // CNOT ring: (0,1), (1,2), (2,3), (3,0) — swap target bit when control set
#pragma unroll
        for (int q = 0; q < 4; ++q) {
            int t = (q + 1) & 3;
            int cmask = 8 >> q;
            int tmask = 8 >> t;
#pragma unroll
            for (int m = 0; m < 16; ++m) {
                if (!(m & cmask) || (m & tmask)) continue;
                int m1 = m ^ tmask;
                float tr = re[m]; re[m] = re[m1]; re[m1] = tr;
                float ti = im[m]; im[m] = im[m1]; im[m1] = ti;
            }
        }
    }

    // Probabilities and <Z_q>
    float p[16];
#pragma unroll
    for (int m = 0; m < 16; ++m) {
        p[m] = re[m] * re[m] + im[m] * im[m];
    }

    float z[4];
#pragma unroll
    for (int q = 0; q < 4; ++q) {
        int mask = 8 >> q;
        float acc = 0.0f;
#pragma unroll
        for (int m = 0; m < 16; ++m) {
            acc += (m & mask) ? -p[m] : p[m];
        }
        z[q] = acc;
    }

    float4 o = make_float4(z[0], z[1], z[2], z[3]);
    *(float4*)(out + (size_t)n * 4) = o;
}

extern "C" void kernel_launch(void* const* d_in, const int* in_sizes, int n_in,
                              void* d_out, int out_size, void* d_ws, size_t ws_size,
                              hipStream_t stream) {
    const float* x  = (const float*)d_in[0];
    const float* qw = (const float*)d_in[1];
    float* out = (float*)d_out;
    int n_total = out_size / 4;  // 524288 patches
    dim3 block(256);
    dim3 grid((n_total + 255) / 256);
    hipLaunchKernelGGL(qlayer_kernel, grid, block, 0, stream, x, qw, out, n_total);
}

// Round 2
// 65.639 us; speedup vs baseline: 1.0871x; 1.0871x over previous
//
#include <hip/hip_runtime.h>

// One thread per 2x2 patch: simulate a 4-qubit circuit (16 complex amps,
// fully unrolled into registers), output <Z_q> for q=0..3.
//
// Index convention: amplitude m = i*8 + j*4 + k*2 + l where i..l are
// qubits 0..3 -> qubit q lives at bit (3-q), mask = 8 >> q.
//
// Trig via raw v_sin_f32/v_cos_f32 (input in REVOLUTIONS, sin(2*pi*x)):
//   patch half-angle = patch*pi/4  -> rev = patch * 0.125  (exact pow2 scale)
//   weight half-angle = w*0.5      -> rev = w * (0.5/(2*pi))
// Avoids __sincosf's pointer outputs, which can demote the unrolled
// register arrays to scratch via an un-inlined ocml call.

__global__ __launch_bounds__(256) void qlayer_kernel(
    const float* __restrict__ x,     // (32, 256, 256, 1)
    const float* __restrict__ qw,    // (2, 4)
    float* __restrict__ out,         // (32, 128, 128, 4)
    int n_total)
{
    int n = blockIdx.x * blockDim.x + threadIdx.x;
    if (n >= n_total) return;

    int ow = n & 127;
    int oh = (n >> 7) & 127;
    int b  = n >> 14;

    // 2x2 stride-2 patch, row-major within patch
    const float* row0 = x + ((size_t)(b * 256 + 2 * oh) * 256 + 2 * ow);
    const float* row1 = row0 + 256;
    float2 p0 = *(const float2*)row0;   // angles 0, 1
    float2 p1 = *(const float2*)row1;   // angles 2, 3

    // Revolutions for the RY half-angles (exact *0.125)
    float rev[4] = { p0.x * 0.125f, p0.y * 0.125f, p1.x * 0.125f, p1.y * 0.125f };

    // Per-qubit RY amplitudes on |0>: [cos, sin]
    float vc[4], vs[4];
#pragma unroll
    for (int q = 0; q < 4; ++q) {
        vs[q] = __builtin_amdgcn_sinf(rev[q]);
        vc[q] = __builtin_amdgcn_cosf(rev[q]);
    }

    // Product state (real), im = 0 (compiler folds zeros through layer 1)
    float re[16], im[16];
#pragma unroll
    for (int i = 0; i < 2; ++i) {
        float v0 = i ? vs[0] : vc[0];
#pragma unroll
        for (int j = 0; j < 2; ++j) {
            float v01 = v0 * (j ? vs[1] : vc[1]);
#pragma unroll
            for (int k = 0; k < 2; ++k) {
                float v012 = v01 * (k ? vs[2] : vc[2]);
#pragma unroll
                for (int l = 0; l < 2; ++l) {
                    int m = i * 8 + j * 4 + k * 2 + l;
                    re[m] = v012 * (l ? vs[3] : vc[3]);
                    im[m] = 0.0f;
                }
            }
        }
    }

    // Gate half-angle cos/sin for all (layer, qubit): w*0.5 rad -> rev
    const float W_REV = 0.07957747154594767f;  // 0.5/(2*pi)
    float gc[8], gs[8];
#pragma unroll
    for (int i = 0; i < 8; ++i) {
        float r = qw[i] * W_REV;
        gs[i] = __builtin_amdgcn_sinf(r);
        gc[i] = __builtin_amdgcn_cosf(r);
    }

#pragma unroll
    for (int l = 0; l < 2; ++l) {
        // RX(w) on each qubit: [[c, -is], [-is, c]]
#pragma unroll
        for (int q = 0; q < 4; ++q) {
            float c = gc[l * 4 + q];
            float s = gs[l * 4 + q];
            int mask = 8 >> q;
#pragma unroll
            for (int m = 0; m < 16; ++m) {
                if (m & mask) continue;
                int m1 = m | mask;
                float r0 = re[m],  i0 = im[m];
                float r1 = re[m1], i1 = im[m1];
                // new0 = c*a0 - i*s*a1 ; new1 = -i*s*a0 + c*a1
                re[m]  = c * r0 + s * i1;
                im[m]  = c * i0 - s * r1;
                re[m1] = c * r1 + s * i0;
                im[m1] = c * i1 - s * r0;
            }
        }
        // CNOT ring: (0,1), (1,2), (2,3), (3,0) — swap target bit when control set
        // (pure register renames after unrolling)
#pragma unroll
        for (int q = 0; q < 4; ++q) {
            int t = (q + 1) & 3;
            int cmask = 8 >> q;
            int tmask = 8 >> t;
#pragma unroll
            for (int m = 0; m < 16; ++m) {
                if (!(m & cmask) || (m & tmask)) continue;
                int m1 = m ^ tmask;
                float tr = re[m]; re[m] = re[m1]; re[m1] = tr;
                float ti = im[m]; im[m] = im[m1]; im[m1] = ti;
            }
        }
    }

    // Probabilities
    float p[16];
#pragma unroll
    for (int m = 0; m < 16; ++m) {
        p[m] = re[m] * re[m] + im[m] * im[m];
    }

    // Butterfly marginals: z3 from pairs along bit0, then collapse, etc.
    float z3 = 0.0f, z2 = 0.0f, z1 = 0.0f, z0;
    float a[8], bb[4], cc[2];
#pragma unroll
    for (int j = 0; j < 8; ++j) {
        z3 += p[2 * j] - p[2 * j + 1];
        a[j] = p[2 * j] + p[2 * j + 1];
    }
#pragma unroll
    for (int j = 0; j < 4; ++j) {
        z2 += a[2 * j] - a[2 * j + 1];
        bb[j] = a[2 * j] + a[2 * j + 1];
    }
#pragma unroll
    for (int j = 0; j < 2; ++j) {
        z1 += bb[2 * j] - bb[2 * j + 1];
        cc[j] = bb[2 * j] + bb[2 * j + 1];
    }
    z0 = cc[0] - cc[1];

    float4 o = make_float4(z0, z1, z2, z3);
    *(float4*)(out + (size_t)n * 4) = o;
}

extern "C" void kernel_launch(void* const* d_in, const int* in_sizes, int n_in,
                              void* d_out, int out_size, void* d_ws, size_t ws_size,
                              hipStream_t stream) {
    const float* x  = (const float*)d_in[0];
    const float* qw = (const float*)d_in[1];
    float* out = (float*)d_out;
    int n_total = out_size / 4;  // 524288 patches
    dim3 block(256);
    dim3 grid((n_total + 255) / 256);
    hipLaunchKernelGGL(qlayer_kernel, grid, block, 0, stream, x, qw, out, n_total);
}

// Round 3
// 61.731 us; speedup vs baseline: 1.1559x; 1.0633x over previous
//
#include <hip/hip_runtime.h>

// Heisenberg-picture evaluation: propagate Z_q backward through
//   U = Cring2 * Rx2 * Cring1 * Rx1   (Cring = C(3,0)C(2,3)C(1,2)C(0,1))
// CNOT conj maps Pauli strings to Pauli strings (with signs);
// RX(w)+ Z RX(w) = cos(w) Z + sin(w) Y,  Y -> cos(w) Y - sin(w) Z.
// Initial state is a real RY product state: <Y>=0, <Z_j>=cos th_j,
// <X_j>=sin th_j with th_j = x_j*pi/2. So after the layer-1 RX
// conjugation each string keeps exactly one non-Y branch:
//   final Z on qubit j -> gz_j = cos(w1_j) cos th_j
//   final Y on qubit j -> gy_j = -sin(w1_j) cos th_j
//   final X on qubit j -> X_j  = sin th_j
// Full 36-term expansion (hand-derived, sign-checked) factorizes below.
// c_j,s_j = cos/sin of FULL layer-2 angles; all weight trig is wave-uniform.

__global__ __launch_bounds__(256) void qlayer_kernel(
    const float* __restrict__ x,     // (32, 256, 256, 1)
    const float* __restrict__ qw,    // (2, 4)
    float* __restrict__ out,         // (32, 128, 128, 4)
    int n_total)
{
    int n = blockIdx.x * blockDim.x + threadIdx.x;
    if (n >= n_total) return;

    int ow = n & 127;
    int oh = (n >> 7) & 127;
    int b  = n >> 14;

    const float* row0 = x + ((size_t)(b * 256 + 2 * oh) * 256 + 2 * ow);
    float2 p0 = *(const float2*)row0;          // angles 0,1
    float2 p1 = *(const float2*)(row0 + 256);  // angles 2,3

    // th_j = x_j*pi/2  -> revolutions = x_j * 0.25 (exact pow2 scale)
    float xv[4] = { p0.x, p0.y, p1.x, p1.y };
    float Cth[4], Sth[4];
#pragma unroll
    for (int j = 0; j < 4; ++j) {
        float r = xv[j] * 0.25f;
        Sth[j] = __builtin_amdgcn_sinf(r);
        Cth[j] = __builtin_amdgcn_cosf(r);
    }

    // Weight trig: FULL angles, rev = w / (2*pi). Uniform across wave.
    const float INV2PI = 0.15915494309189535f;
    float C1[4], S1[4], C2[4], S2[4];
#pragma unroll
    for (int j = 0; j < 4; ++j) {
        float r1 = qw[j]     * INV2PI;   // layer 1 (applied first)
        float r2 = qw[4 + j] * INV2PI;   // layer 2
        S1[j] = __builtin_amdgcn_sinf(r1);
        C1[j] = __builtin_amdgcn_cosf(r1);
        S2[j] = __builtin_amdgcn_sinf(r2);
        C2[j] = __builtin_amdgcn_cosf(r2);
    }

    float gz[4], gy[4], X[4];
#pragma unroll
    for (int j = 0; j < 4; ++j) {
        gz[j] = C1[j] * Cth[j];
        gy[j] = -S1[j] * Cth[j];
        X[j]  = Sth[j];
    }

    // ---- z1:  Z1 -> Z0 Z1 -> 4 strings ----
    float a0  = C2[0] * gz[0];
    float b0  = S2[0] * gy[0];
    float in1 = fmaf(b0, X[1], a0);        // c0 gz0 + s0 gy0 X1
    float in2 = fmaf(a0, X[1], b0);        // c0 gz0 X1 + s0 gy0
    float z1  = gz[3] * fmaf(S2[1] * gy[2], in2, C2[1] * gz[2] * in1);

    // ---- shared for z0/z2:  P,Q,R,T over qubits 2,3 ----
    float m23a = X[2] * gz[3];
    float m23b = X[2] * gy[3];
    float P = fmaf(S2[2], m23b,  C2[2] * gz[3]);   // c2 gz3 + s2 X2 gy3
    float R = fmaf(C2[2], m23a,  S2[2] * gy[3]);   // c2 X2 gz3 + s2 gy3
    float Q = fmaf(S2[2], m23a, -C2[2] * gy[3]);   // s2 X2 gz3 - c2 gy3
    float T = fmaf(C2[2], m23b, -S2[2] * gz[3]);   // c2 X2 gy3 - s2 gz3

    float u1 = C2[1] * gz[1], u2 = S2[1] * gy[1];
    float u3 = C2[1] * gy[1], u4 = S2[1] * gz[1];
    float M1 = fmaf(u2, R, u1 * P);                // c1 gz1 P + s1 gy1 R
    float M2 = fmaf(u4, T, u3 * Q);                // c1 gy1 Q + s1 gz1 T
    float M3 = fmaf(-u4, R, u3 * P);               // c1 gy1 P - s1 gz1 R

    // z0 = c3 gz0 M1 + s3 gy0 M2
    float z0 = fmaf(S2[3] * gy[0], M2, C2[3] * gz[0] * M1);
    // z2 = c0 M1 + s0 X0 M3
    float z2 = fmaf(S2[0] * X[0], M3, C2[0] * M1);

    // ---- z3: 16 strings, factorized over qubits 2,3 then 0,1 ----
    float m2a = X[3] * gz[2];
    float m2b = X[3] * gy[2];
    float U  = fmaf(S2[2], m2b,  C2[2] * gz[2]);   // c2 gz2 + s2 gy2 X3
    float V  = fmaf(C2[2], m2a,  S2[2] * gy[2]);   // c2 gz2 X3 + s2 gy2
    float W  = fmaf(-S2[2], m2a, C2[2] * gy[2]);   // c2 gy2 - s2 gz2 X3
    float Xp = fmaf(C2[2], m2b, -S2[2] * gz[2]);   // c2 gy2 X3 - s2 gz2

    float cc = C2[0] * C2[3], ss = S2[0] * S2[3];
    float cs = C2[0] * S2[3], sc = S2[0] * C2[3];
    float A  = fmaf(-ss, V,  cc * U);
    float Bq = fmaf(-ss, Xp, cc * W);
    float D  = fmaf(sc, W,  cs * Xp);
    float E  = fmaf(sc, U,  cs * V);
    float t1 = fmaf(S2[1] * X[1], Bq, C2[1] * A);
    float t2 = fmaf(C2[1] * X[1], E,  S2[1] * D);
    float z3 = fmaf(gy[0], t2, gz[0] * t1);

    *(float4*)(out + (size_t)n * 4) = make_float4(z0, z1, z2, z3);
}

extern "C" void kernel_launch(void* const* d_in, const int* in_sizes, int n_in,
                              void* d_out, int out_size, void* d_ws, size_t ws_size,
                              hipStream_t stream) {
    const float* x  = (const float*)d_in[0];
    const float* qw = (const float*)d_in[1];
    float* out = (float*)d_out;
    int n_total = out_size / 4;  // 524288 patches
    dim3 block(256);
    dim3 grid((n_total + 255) / 256);
    hipLaunchKernelGGL(qlayer_kernel, grid, block, 0, stream, x, qw, out, n_total);
}